// Round 3
// baseline (555.528 us; speedup 1.0000x reference)
//
#include <hip/hip_runtime.h>
#include <math.h>

#define HW 12544   // 112*112
#define IMW 112

// async global->LDS, 16B per lane: LDS dest = uniform base + lane*16
#define GLOAD_LDS16(gp, lp) __builtin_amdgcn_global_load_lds( \
    (const __attribute__((address_space(1))) void*)(gp),      \
    (__attribute__((address_space(3))) void*)(lp), 16, 0, 0)

// numpy pairwise add.reduce (n=16) over squares, then norm clamp — bitwise np.linalg.norm
__device__ __forceinline__ float np_norm16(const float* a) {
    float q[16];
    #pragma unroll
    for (int i = 0; i < 16; ++i) q[i] = __fmul_rn(a[i], a[i]);
    float r0 = __fadd_rn(q[0], q[8]),  r1 = __fadd_rn(q[1], q[9]);
    float r2 = __fadd_rn(q[2], q[10]), r3 = __fadd_rn(q[3], q[11]);
    float r4 = __fadd_rn(q[4], q[12]), r5 = __fadd_rn(q[5], q[13]);
    float r6 = __fadd_rn(q[6], q[14]), r7 = __fadd_rn(q[7], q[15]);
    float s = __fadd_rn(__fadd_rn(__fadd_rn(r0, r1), __fadd_rn(r2, r3)),
                        __fadd_rn(__fadd_rn(r4, r5), __fadd_rn(r6, r7)));
    return fmaxf(__fsqrt_rn(s), 1e-12f);
}

// =====================================================================
// K1: per-problem f/v GEMM (direct pipelined loads) + clustering P0-P5.
// Writes agg[49][16], simv[256], bidx[256] per problem to workspace.
// =====================================================================
__global__ __launch_bounds__(256, 4)
void lc_cluster(const float* __restrict__ x,
                const float* __restrict__ fw, const float* __restrict__ fb,
                const float* __restrict__ vw, const float* __restrict__ vb,
                const float* __restrict__ alpha, const float* __restrict__ beta,
                float* __restrict__ aggws, float* __restrict__ simvws,
                int* __restrict__ bidxws)
{
    // U (6656 floats = 26 KB), phase-aliased:
    //  P1: fw_s[2048]=U[0:2048] | vw_s[2048]=U[2048:4096]
    //  P2-P5: f_s[4096]=U[0:4096] | cent_s[784]=U[4096:4880] | ncf_s[784]=U[4880:5664]
    //         vcent_s[784]=U[5664:6448] | simsum_s[49]=U[6448:6497]
    __shared__ __attribute__((aligned(16))) float U[6656];
    __shared__ __attribute__((aligned(16))) float agg_s[784];

    float* fw_s    = U;
    float* vw_s    = U + 2048;
    float* f_s     = U;
    float* cent_s  = U + 4096;
    float* ncf_s   = U + 4880;
    float* vcent_s = U + 5664;
    float* simsum_s= U + 6448;

    const int t  = threadIdx.x;
    const int py = t >> 4, px = t & 15;
    const int b  = blockIdx.x;
    const int batch = b / 49;
    const int rr = b % 49;
    const int gi = rr / 7, gj = rr % 7;
    const int row = gi*16 + py, col = gj*16 + px;

    // ---- P0: stage weights (float4), zero accumulators (vcent/simsum don't alias weights) ----
    for (int i = t; i < 512; i += 256) {
        ((float4*)fw_s)[i] = ((const float4*)fw)[i];
        ((float4*)vw_s)[i] = ((const float4*)vw)[i];
    }
    for (int i = t; i < 784; i += 256) { vcent_s[i] = 0.f; agg_s[i] = 0.f; }
    if (t < 49) simsum_s[t] = 0.f;
    __syncthreads();

    // ---- P1: f (bitwise-np fp32: ascending c, separate mul/add, bias last);
    //          v (fast fmaf). Direct global loads, software-pipelined 1 chunk
    //          ahead, NO barriers inside the loop.
    const float* xp = x + (size_t)batch*256*HW + (size_t)row*IMW + col;
    const float* yp = xp + (size_t)128*HW;

    float facc[16], vacc[16];
    #pragma unroll
    for (int o = 0; o < 16; ++o) { facc[o] = 0.f; vacc[o] = vb[o]; }

    const float* xq = xp;
    const float* yq = yp;
    float xc0 = xq[0], xc1 = xq[HW], xc2 = xq[2*HW], xc3 = xq[3*HW];
    float yc0 = yq[0], yc1 = yq[HW], yc2 = yq[2*HW], yc3 = yq[3*HW];

    for (int c4 = 0; c4 < 32; ++c4) {
        xq += 4*HW; yq += 4*HW;
        float xn0, xn1, xn2, xn3, yn0, yn1, yn2, yn3;
        if (c4 < 31) {
            xn0 = xq[0]; xn1 = xq[HW]; xn2 = xq[2*HW]; xn3 = xq[3*HW];
            yn0 = yq[0]; yn1 = yq[HW]; yn2 = yq[2*HW]; yn3 = yq[3*HW];
        } else {
            xn0 = xn1 = xn2 = xn3 = 0.f;
            yn0 = yn1 = yn2 = yn3 = 0.f;
        }
        #pragma unroll
        for (int o = 0; o < 16; ++o) {
            const float* ar = fw_s + o*128 + c4*4;
            float s = facc[o];
            s = __fadd_rn(s, __fmul_rn(ar[0], xc0));
            s = __fadd_rn(s, __fmul_rn(ar[1], xc1));
            s = __fadd_rn(s, __fmul_rn(ar[2], xc2));
            s = __fadd_rn(s, __fmul_rn(ar[3], xc3));
            facc[o] = s;
            const float* cr = vw_s + o*128 + c4*4;
            vacc[o] = fmaf(cr[3], yc3, fmaf(cr[2], yc2, fmaf(cr[1], yc1, fmaf(cr[0], yc0, vacc[o]))));
        }
        xc0 = xn0; xc1 = xn1; xc2 = xn2; xc3 = xn3;
        yc0 = yn0; yc1 = yn1; yc2 = yn2; yc3 = yn3;
    }
    #pragma unroll
    for (int o = 0; o < 16; ++o) facc[o] = __fadd_rn(facc[o], fb[o]);

    __syncthreads();   // weights dead; f_s region reusable

    // ---- P2a: stage f to LDS + v pooling (fp32 atomics, value path) ----
    {
        float* fr = f_s + t*16;
        #pragma unroll
        for (int o = 0; o < 16; ++o) fr[o] = facc[o];
    }
    {
        const int   wss[7] = {0,2,4,6,9,11,13};
        const int   wee[7] = {3,5,7,10,12,14,16};
        const float wiv[7] = {1.f/3.f,1.f/3.f,1.f/3.f,0.25f,1.f/3.f,1.f/3.f,1.f/3.f};
        for (int i = 0; i < 7; ++i) {
            if (py < wss[i] || py >= wee[i]) continue;
            for (int j = 0; j < 7; ++j) {
                if (px < wss[j] || px >= wee[j]) continue;
                const float sc = wiv[i]*wiv[j];
                float* vb2 = vcent_s + (i*7+j)*16;
                #pragma unroll
                for (int o = 0; o < 16; ++o) atomicAdd(vb2 + o, vacc[o]*sc);
            }
        }
    }
    __syncthreads();

    // ---- P2b: centers, bitwise-np: per-term (Pw*f)*Ph, w-outer h-inner ascending ----
    {
        const int   wss[7] = {0,2,4,6,9,11,13};
        const int   wee[7] = {3,5,7,10,12,14,16};
        const float wiv[7] = {1.f/3.f,1.f/3.f,1.f/3.f,0.25f,1.f/3.f,1.f/3.f,1.f/3.f};
        for (int T = t; T < 784; T += 256) {
            int m = T >> 4, o = T & 15;
            int i = m / 7, j = m % 7;
            float pwv = wiv[i], phv = wiv[j];
            float s = 0.f;
            for (int r = wss[i]; r < wee[i]; ++r)
                for (int cc = wss[j]; cc < wee[j]; ++cc)
                    s = __fadd_rn(s, __fmul_rn(__fmul_rn(pwv, f_s[(r*16 + cc)*16 + o]), phv));
            cent_s[T] = s;
        }
    }
    __syncthreads();

    // ---- P3: normalize centers (bitwise np.linalg.norm + divide) ----
    if (t < 49) {
        float rowv[16];
        #pragma unroll
        for (int o = 0; o < 16; ++o) rowv[o] = cent_s[t*16 + o];
        float n = np_norm16(rowv);
        #pragma unroll
        for (int o = 0; o < 16; ++o) ncf_s[t*16 + o] = __fdiv_rn(rowv[o], n);
    }
    __syncthreads();

    // ---- P4: fp32 sim (bitwise-ish) + first-max argmax; value-path aggregation ----
    float nff[16];
    {
        float n = np_norm16(facc);
        #pragma unroll
        for (int o = 0; o < 16; ++o) nff[o] = __fdiv_rn(facc[o], n);
    }
    const float al = alpha[0], be = beta[0];
    float best = -1.0f; int bidx = 0;
    for (int m = 0; m < 49; ++m) {
        const float* cm = ncf_s + m*16;
        float s = 0.f;
        #pragma unroll
        for (int o = 0; o < 16; ++o) s = __fadd_rn(s, __fmul_rn(cm[o], nff[o]));
        float z = __fadd_rn(be, __fmul_rn(al, s));
        float sim = __fdiv_rn(1.0f, __fadd_rn(1.0f, expf(-z)));
        if (sim > best) { best = sim; bidx = m; }   // first-max == np.argmax
    }
    const float simv = best;
    simvws[b*256 + t] = simv;
    bidxws[b*256 + t] = bidx;
    atomicAdd(&simsum_s[bidx], simv);
    {
        float* ab = agg_s + bidx*16;
        #pragma unroll
        for (int o = 0; o < 16; ++o) atomicAdd(ab + o, simv*vacc[o]);
    }
    __syncthreads();

    // ---- P5: finalize agg, write to workspace ----
    for (int T = t; T < 784; T += 256) {
        int m = T >> 4;
        aggws[b*784 + T] = (agg_s[T] + vcent_s[T]) / (simsum_s[m] + 1.0f);
    }
}

// =====================================================================
// K3: output projection. grid = 784 problems x 4 channel-groups of 64.
// out[o,pixel] = simv[pixel] * (pw[o,:].agg[bidx[pixel],:]) + pb[o]
// =====================================================================
__global__ __launch_bounds__(256, 8)
void lc_out(const float* __restrict__ pw, const float* __restrict__ pb,
            const float* __restrict__ aggws, const float* __restrict__ simvws,
            const int* __restrict__ bidxws, float* __restrict__ out)
{
    __shared__ __attribute__((aligned(16))) float agg_l[784];
    __shared__ __attribute__((aligned(16))) float pw_l[1024];    // 64 oc x 16
    __shared__ __attribute__((aligned(16))) float Pagg_l[64*49];
    __shared__ __attribute__((aligned(16))) float simv_l[256];
    __shared__ __attribute__((aligned(16))) int   bidx_l[256];
    __shared__ __attribute__((aligned(16))) float pb_l[64];

    const int t    = threadIdx.x;
    const int wave = t >> 6, lane = t & 63;
    const int bid  = blockIdx.x;
    const int prob = bid >> 2, cg = bid & 3;
    const int batch = prob / 49;
    const int rr = prob % 49;
    const int gi = rr / 7, gj = rr % 7;

    for (int i = t; i < 784; i += 256) agg_l[i] = aggws[prob*784 + i];
    for (int i = t; i < 1024; i += 256) pw_l[i] = pw[cg*1024 + i];
    simv_l[t] = simvws[prob*256 + t];
    bidx_l[t] = bidxws[prob*256 + t];
    if (t < 64) pb_l[t] = pb[cg*64 + t];
    __syncthreads();

    // Pagg[oc][m] = pw[cg*64+oc,:] . agg[m,:]  (same fmaf chain as before)
    {
        const int oc_l = t >> 2, q = t & 3;
        const int mq0[4] = {0,13,25,37};
        const int mq1[4] = {13,25,37,49};
        const float4* pg = (const float4*)(pw_l + oc_l*16);
        const float4 q0 = pg[0], q1 = pg[1], q2 = pg[2], q3 = pg[3];
        float* pr = Pagg_l + oc_l*49;
        for (int m = mq0[q]; m < mq1[q]; ++m) {
            const float4* am = (const float4*)(agg_l + m*16);
            float4 a0 = am[0], a1 = am[1], a2 = am[2], a3 = am[3];
            float d;
            d = q0.x*a0.x;
            d = fmaf(q0.y,a0.y,d); d = fmaf(q0.z,a0.z,d); d = fmaf(q0.w,a0.w,d);
            d = fmaf(q1.x,a1.x,d); d = fmaf(q1.y,a1.y,d); d = fmaf(q1.z,a1.z,d);
            d = fmaf(q1.w,a1.w,d); d = fmaf(q2.x,a2.x,d); d = fmaf(q2.y,a2.y,d);
            d = fmaf(q2.z,a2.z,d); d = fmaf(q2.w,a2.w,d); d = fmaf(q3.x,a3.x,d);
            d = fmaf(q3.y,a3.y,d); d = fmaf(q3.z,a3.z,d); d = fmaf(q3.w,a3.w,d);
            pr[m] = d;
        }
    }
    __syncthreads();

    // stores: lane q handles pixel quad (row q>>2, cols (q&3)*4..+3) -> float4
    float* out_tile = out + (size_t)batch*256*HW + (size_t)(gi*16)*IMW + gj*16;
    float* op4 = out_tile + (lane >> 2)*IMW + (lane & 3)*4;
    const float4 sv4 = *(const float4*)(simv_l + (lane << 2));
    const int4   bi4 = *(const int4*)  (bidx_l + (lane << 2));

    #pragma unroll 8
    for (int k = 0; k < 16; ++k) {
        const int oc_l = (wave << 4) + k;
        const int o    = (cg << 6) + oc_l;
        const float* pr = Pagg_l + oc_l*49;
        const float pbo = pb_l[oc_l];
        float4 r;
        r.x = fmaf(sv4.x, pr[bi4.x], pbo);
        r.y = fmaf(sv4.y, pr[bi4.y], pbo);
        r.z = fmaf(sv4.z, pr[bi4.z], pbo);
        r.w = fmaf(sv4.w, pr[bi4.w], pbo);
        *(float4*)(op4 + (size_t)o*HW) = r;
    }
}

// =====================================================================
// Fallback: verified R1 monolithic kernel (used if workspace too small)
// =====================================================================
__global__ __launch_bounds__(256, 4)
void lc_fused(const float* __restrict__ x,
              const float* __restrict__ fw, const float* __restrict__ fb,
              const float* __restrict__ vw, const float* __restrict__ vb,
              const float* __restrict__ pw, const float* __restrict__ pb,
              const float* __restrict__ alpha, const float* __restrict__ beta,
              float* __restrict__ out)
{
    __shared__ __attribute__((aligned(16))) float U[8192];
    __shared__ __attribute__((aligned(16))) float agg_s[784];
    __shared__ __attribute__((aligned(16))) float pb_s[256];
    __shared__ __attribute__((aligned(16))) float simv_s[256];
    __shared__ __attribute__((aligned(16))) int   bidx_s[256];

    float* fw_s    = U;
    float* vw_s    = U + 2048;
    float* xs      = U + 4096;
    float* f_s     = U;
    float* cent_s  = U + 4096;
    float* ncf_s   = U + 4880;
    float* vcent_s = U + 5664;
    float* simsum_s= U + 6448;
    float* Pagg_s  = U;

    const int t    = threadIdx.x;
    const int wave = t >> 6, lane = t & 63;
    const int py = t >> 4, px = t & 15;
    const int b  = blockIdx.x;
    const int batch = b / 49;
    const int rr = b % 49;
    const int gi = rr / 7, gj = rr % 7;

    for (int i = t; i < 512; i += 256) {
        ((float4*)fw_s)[i] = ((const float4*)fw)[i];
        ((float4*)vw_s)[i] = ((const float4*)vw)[i];
    }
    pb_s[t] = pb[t];
    for (int i = t; i < 784; i += 256) agg_s[i] = 0.f;

    const float* xbase = x + (size_t)batch*256*HW
                       + (size_t)(gi*16 + (lane >> 2))*IMW + gj*16 + (lane & 3)*4;

    float facc[16], vacc[16];
    #pragma unroll
    for (int o = 0; o < 16; ++o) { facc[o] = 0.f; vacc[o] = vb[o]; }

    for (int ch = 0; ch < 16; ++ch) {
        #pragma unroll
        for (int k = 0; k < 4; ++k) {
            const int sc = (wave << 2) + k;
            const int gc = (sc < 8) ? (ch*8 + sc) : (120 + ch*8 + sc);
            GLOAD_LDS16(xbase + (size_t)gc*HW, xs + (sc << 8));
        }
        __syncthreads();

        #pragma unroll
        for (int half = 0; half < 2; ++half) {
            const int c4 = (ch << 1) + half;
            const float* xf = xs + ((half*4) << 8) + t;
            const float* xv = xs + 2048 + ((half*4) << 8) + t;
            const float x0 = xf[0], x1 = xf[256], x2 = xf[512], x3 = xf[768];
            const float y0 = xv[0], y1 = xv[256], y2 = xv[512], y3 = xv[768];
            #pragma unroll
            for (int o = 0; o < 16; ++o) {
                const float* ar = fw_s + o*128 + c4*4;
                float s = facc[o];
                s = __fadd_rn(s, __fmul_rn(ar[0], x0));
                s = __fadd_rn(s, __fmul_rn(ar[1], x1));
                s = __fadd_rn(s, __fmul_rn(ar[2], x2));
                s = __fadd_rn(s, __fmul_rn(ar[3], x3));
                facc[o] = s;
                const float* cr = vw_s + o*128 + c4*4;
                vacc[o] = fmaf(cr[3], y3, fmaf(cr[2], y2, fmaf(cr[1], y1, fmaf(cr[0], y0, vacc[o]))));
            }
        }
        __syncthreads();
    }
    #pragma unroll
    for (int o = 0; o < 16; ++o) facc[o] = __fadd_rn(facc[o], fb[o]);

    for (int i = t; i < 784; i += 256) vcent_s[i] = 0.f;
    if (t < 49) simsum_s[t] = 0.f;
    __syncthreads();

    {
        float* fr = f_s + t*16;
        #pragma unroll
        for (int o = 0; o < 16; ++o) fr[o] = facc[o];
    }
    {
        const int   wss[7] = {0,2,4,6,9,11,13};
        const int   wee[7] = {3,5,7,10,12,14,16};
        const float wiv[7] = {1.f/3.f,1.f/3.f,1.f/3.f,0.25f,1.f/3.f,1.f/3.f,1.f/3.f};
        for (int i = 0; i < 7; ++i) {
            if (py < wss[i] || py >= wee[i]) continue;
            for (int j = 0; j < 7; ++j) {
                if (px < wss[j] || px >= wee[j]) continue;
                const float sc = wiv[i]*wiv[j];
                float* vb2 = vcent_s + (i*7+j)*16;
                #pragma unroll
                for (int o = 0; o < 16; ++o) atomicAdd(vb2 + o, vacc[o]*sc);
            }
        }
    }
    __syncthreads();

    {
        const int   wss[7] = {0,2,4,6,9,11,13};
        const int   wee[7] = {3,5,7,10,12,14,16};
        const float wiv[7] = {1.f/3.f,1.f/3.f,1.f/3.f,0.25f,1.f/3.f,1.f/3.f,1.f/3.f};
        for (int T = t; T < 784; T += 256) {
            int m = T >> 4, o = T & 15;
            int i = m / 7, j = m % 7;
            float pwv = wiv[i], phv = wiv[j];
            float s = 0.f;
            for (int r = wss[i]; r < wee[i]; ++r)
                for (int cc = wss[j]; cc < wee[j]; ++cc)
                    s = __fadd_rn(s, __fmul_rn(__fmul_rn(pwv, f_s[(r*16 + cc)*16 + o]), phv));
            cent_s[T] = s;
        }
    }
    __syncthreads();

    if (t < 49) {
        float rowv[16];
        #pragma unroll
        for (int o = 0; o < 16; ++o) rowv[o] = cent_s[t*16 + o];
        float n = np_norm16(rowv);
        #pragma unroll
        for (int o = 0; o < 16; ++o) ncf_s[t*16 + o] = __fdiv_rn(rowv[o], n);
    }
    __syncthreads();

    float nff[16];
    {
        float n = np_norm16(facc);
        #pragma unroll
        for (int o = 0; o < 16; ++o) nff[o] = __fdiv_rn(facc[o], n);
    }
    const float al = alpha[0], be = beta[0];
    float best = -1.0f; int bidx = 0;
    for (int m = 0; m < 49; ++m) {
        const float* cm = ncf_s + m*16;
        float s = 0.f;
        #pragma unroll
        for (int o = 0; o < 16; ++o) s = __fadd_rn(s, __fmul_rn(cm[o], nff[o]));
        float z = __fadd_rn(be, __fmul_rn(al, s));
        float sim = __fdiv_rn(1.0f, __fadd_rn(1.0f, expf(-z)));
        if (sim > best) { best = sim; bidx = m; }
    }
    const float simv = best;
    simv_s[t] = simv;
    bidx_s[t] = bidx;
    atomicAdd(&simsum_s[bidx], simv);
    {
        float* ab = agg_s + bidx*16;
        #pragma unroll
        for (int o = 0; o < 16; ++o) atomicAdd(ab + o, simv*vacc[o]);
    }
    __syncthreads();

    for (int T = t; T < 784; T += 256) {
        int m = T >> 4;
        agg_s[T] = (agg_s[T] + vcent_s[T]) / (simsum_s[m] + 1.0f);
    }
    __syncthreads();

    float* out_tile = out + (size_t)batch*256*HW + (size_t)(gi*16)*IMW + gj*16;
    float* op4 = out_tile + (lane >> 2)*IMW + (lane & 3)*4;
    const float4 sv4 = *(const float4*)(simv_s + (lane << 2));
    const int4   bi4 = *(const int4*)  (bidx_s + (lane << 2));

    const int oc6 = t >> 1;
    const int m0  = (t & 1) ? 25 : 0;
    const int m1  = (t & 1) ? 49 : 25;

    #pragma unroll
    for (int half = 0; half < 2; ++half) {
        {
            const int o = (half << 7) + oc6;
            const float4* pg = (const float4*)(pw + o*16);
            const float4 q0 = pg[0], q1 = pg[1], q2 = pg[2], q3 = pg[3];
            float* pr = Pagg_s + oc6*49;
            for (int m = m0; m < m1; ++m) {
                const float4* am = (const float4*)(agg_s + m*16);
                float4 a0 = am[0], a1 = am[1], a2 = am[2], a3 = am[3];
                float d;
                d = q0.x*a0.x;
                d = fmaf(q0.y,a0.y,d); d = fmaf(q0.z,a0.z,d); d = fmaf(q0.w,a0.w,d);
                d = fmaf(q1.x,a1.x,d); d = fmaf(q1.y,a1.y,d); d = fmaf(q1.z,a1.z,d);
                d = fmaf(q1.w,a1.w,d); d = fmaf(q2.x,a2.x,d); d = fmaf(q2.y,a2.y,d);
                d = fmaf(q2.z,a2.z,d); d = fmaf(q2.w,a2.w,d); d = fmaf(q3.x,a3.x,d);
                d = fmaf(q3.y,a3.y,d); d = fmaf(q3.z,a3.z,d); d = fmaf(q3.w,a3.w,d);
                pr[m] = d;
            }
        }
        __syncthreads();
        #pragma unroll 8
        for (int k = 0; k < 32; ++k) {
            const int oc = (wave << 5) + k;
            const int o  = (half << 7) + oc;
            const float* pr = Pagg_s + oc*49;
            const float pbo = pb_s[o];
            float4 r;
            r.x = fmaf(sv4.x, pr[bi4.x], pbo);
            r.y = fmaf(sv4.y, pr[bi4.y], pbo);
            r.z = fmaf(sv4.z, pr[bi4.z], pbo);
            r.w = fmaf(sv4.w, pr[bi4.w], pbo);
            *(float4*)(op4 + (size_t)o*HW) = r;
        }
        __syncthreads();
    }
}

extern "C" void kernel_launch(void* const* d_in, const int* in_sizes, int n_in,
                              void* d_out, int out_size, void* d_ws, size_t ws_size,
                              hipStream_t stream) {
    const float* x  = (const float*)d_in[0];
    const float* fw = (const float*)d_in[1];
    const float* fb = (const float*)d_in[2];
    const float* vw = (const float*)d_in[3];
    const float* vb = (const float*)d_in[4];
    const float* pw = (const float*)d_in[5];
    const float* pb = (const float*)d_in[6];
    const float* al = (const float*)d_in[7];
    const float* be = (const float*)d_in[8];
    float* out = (float*)d_out;

    // workspace: agg[784][784] + simv[784][256] + bidx[784][256] = 4.06 MB
    const size_t need = (size_t)784*784*4 + (size_t)784*256*4 + (size_t)784*256*4;
    if (d_ws != nullptr && ws_size >= need) {
        float* aggws  = (float*)d_ws;
        float* simvws = aggws + (size_t)784*784;
        int*   bidxws = (int*)(simvws + (size_t)784*256);
        hipLaunchKernelGGL(lc_cluster, dim3(784), dim3(256), 0, stream,
                           x, fw, fb, vw, vb, al, be, aggws, simvws, bidxws);
        hipLaunchKernelGGL(lc_out, dim3(3136), dim3(256), 0, stream,
                           pw, pb, aggws, simvws, bidxws, out);
    } else {
        hipLaunchKernelGGL(lc_fused, dim3(784), dim3(256), 0, stream,
                           x, fw, fb, vw, vb, pw, pb, al, be, out);
    }
}